// Round 9
// baseline (168.660 us; speedup 1.0000x reference)
//
#include <hip/hip_runtime.h>
#include <cstddef>
#include <cstdint>

// B=8192, T=512, I=4, H=32, O=4 — 2-layer tanh RNN + linear head, fp32 I/O.
constexpr int kB = 8192, kT = 512, kI = 4, kH = 32, kO = 4;

typedef _Float16 f16x8 __attribute__((ext_vector_type(8)));
typedef float    f32x4 __attribute__((ext_vector_type(4)));

#define MFMA(a, b, c) __builtin_amdgcn_mfma_f32_16x16x32_f16((a), (b), (c), 0, 0, 0)

// Barrier waiting on LDS ops only (global loads/stores stay in flight).
__device__ __forceinline__ void bar_lds() {
    asm volatile("s_waitcnt lgkmcnt(0)" ::: "memory");
    __builtin_amdgcn_s_barrier();
    __builtin_amdgcn_sched_barrier(0);
}

__device__ __forceinline__ float fast_tanh(float x) {
    float e = __builtin_amdgcn_exp2f(x * 2.8853900817779268f);  // e^{2x}
    return 1.0f - 2.0f * __builtin_amdgcn_rcpf(e + 1.0f);
}

__device__ __forceinline__ float4 ld4(const float* p) { return *(const float4*)p; }

// A/B fragment from two float4s: elems 0-3 = k {4g..4g+3}, 4-7 = k {16+4g..}.
__device__ __forceinline__ f16x8 pack_frag(float4 lo, float4 hi) {
    f16x8 r;
    r[0] = (_Float16)lo.x; r[1] = (_Float16)lo.y;
    r[2] = (_Float16)lo.z; r[3] = (_Float16)lo.w;
    r[4] = (_Float16)hi.x; r[5] = (_Float16)hi.y;
    r[6] = (_Float16)hi.z; r[7] = (_Float16)hi.w;
    return r;
}

// Assemble a B-operand fragment from two uint2 halves (k 0-15 | k 16-31).
__device__ __forceinline__ f16x8 asm_frag(uint2 lo, uint2 hi) {
    union { f16x8 v; uint2 p[2]; } r;
    r.p[0] = lo; r.p[1] = hi;
    return r.v;
}

// One D-half-tile (4 fp32 rows) -> 8B of B k-slots (2x v_cvt_pkrtz).
__device__ __forceinline__ uint2 pack_half(f32x4 t) {
    uint2 r;
    r.x = __builtin_bit_cast(uint32_t, __builtin_amdgcn_cvt_pkrtz(t[0], t[1]));
    r.y = __builtin_bit_cast(uint32_t, __builtin_amdgcn_cvt_pkrtz(t[2], t[3]));
    return r;
}

// x[t] as B-fragment (k=0..3 live on lane-group 0 only).
__device__ __forceinline__ f16x8 bxpack(float4 xn, bool g0) {
    union { f16x8 v; uint32_t u[4]; } bx;
    bx.u[0] = g0 ? __builtin_bit_cast(uint32_t, __builtin_amdgcn_cvt_pkrtz(xn.x, xn.y)) : 0u;
    bx.u[1] = g0 ? __builtin_bit_cast(uint32_t, __builtin_amdgcn_cvt_pkrtz(xn.z, xn.w)) : 0u;
    bx.u[2] = 0u; bx.u[3] = 0u;
    return bx.v;
}

// 4-wave role split, TWO independent batch tiles per wave (in-wave ILP-2):
//   wave0/1: h0 rows 0-15 / 16-31 for both tiles; wave2/3: h1 + head.
// Tile1's MFMAs and tanh fill tile0's ds_read / MFMA-dep stalls
// deterministically (same wave, independent dataflow). Weights shared.
// Pipeline index i: A computes h0[i]; B computes h1[i-1]; head emits i-2.
__global__ __launch_bounds__(256, 1) void rnn2_quad2(
    const float* __restrict__ X,
    const float* __restrict__ W_ih0, const float* __restrict__ W_hh0,
    const float* __restrict__ b_ih0, const float* __restrict__ b_hh0,
    const float* __restrict__ W_ih1, const float* __restrict__ W_hh1,
    const float* __restrict__ b_ih1, const float* __restrict__ b_hh1,
    const float* __restrict__ W_ll, const float* __restrict__ b_ll,
    float* __restrict__ out)
{
    const int  tid  = threadIdx.x;
    const int  wid  = tid >> 6;        // 0,1 = L0 halves; 2,3 = L1 halves
    const int  half = wid & 1;         // 0: rows 0-15, 1: rows 16-31
    const int  isB  = wid >> 1;
    const int  l    = tid & 63;
    const int  c    = l & 15;          // batch col within tile
    const int  g    = l >> 4;          // k-group
    const bool g0   = (g == 0);
    const int  b0   = blockIdx.x * 32 + c;       // tile 0 batch element
    const int  b1   = b0 + 16;                   // tile 1 batch element
    const int  k0   = 4 * g;
    const int  ro   = half * 16;       // row offset of this wave's half

    __shared__ uint2 h0buf[2][2][2][64];  // [tile][parity][half][lane]
    __shared__ uint2 h1buf[2][2][2][64];

    {   // zero-init both parities (h0[-1]=h1[-1]=h1[-2]=0 fall out)
        uint2* p = (uint2*)h0buf;
        uint2* q = (uint2*)h1buf;
        p[tid] = make_uint2(0u, 0u); p[tid + 256] = make_uint2(0u, 0u);
        q[tid] = make_uint2(0u, 0u); q[tid + 256] = make_uint2(0u, 0u);
    }
    __syncthreads();

    const float4 z4 = make_float4(0.f, 0.f, 0.f, 0.f);

    if (isB == 0) {
        // ======== A-wave: layer 0, rows ro..ro+15, tiles 0 and 1 ========
        const float* wp = W_hh0 + (c + ro) * kH;
        const f16x8 Ahh = pack_frag(ld4(wp + k0), ld4(wp + 16 + k0));
        const f16x8 Aih = pack_frag(g0 ? ld4(W_ih0 + (c + ro) * kI) : z4, z4);
        f32x4 bias0;
#pragma unroll
        for (int r = 0; r < 4; ++r) bias0[r] = b_ih0[ro + k0 + r] + b_hh0[ro + k0 + r];

        uint2 m0 = make_uint2(0u, 0u), m1 = make_uint2(0u, 0u);  // own halves
        f32x4 xcA, xcB;                 // xc[i] per tile
        const float* xp0 = X + (size_t)b0 * (kT * kI);
        const float* xp1 = X + (size_t)b1 * (kT * kI);

        float4 xa0 = ld4(xp0), xb0 = ld4(xp1);
        float4 xa1 = ld4(xp0 + 1 * kI), xb1 = ld4(xp1 + 1 * kI);
        float4 xa2 = ld4(xp0 + 2 * kI), xb2 = ld4(xp1 + 2 * kI);
        float4 xcur0[4], xcur1[4];
#pragma unroll
        for (int u = 0; u < 4; ++u) {
            xcur0[u] = ld4(xp0 + (3 + u) * kI);
            xcur1[u] = ld4(xp1 + (3 + u) * kI);
        }
        xcA = MFMA(Aih, bxpack(xa0, g0), bias0);
        xcB = MFMA(Aih, bxpack(xb0, g0), bias0);

        auto stepA = [&](float4 xn0, float4 xn1, int i) {
            const int rp = (i - 1) & 1, wpar = i & 1;
            // both tiles' sibling reads issue first
            uint2 s0 = h0buf[0][rp][half ^ 1][l];
            uint2 s1 = h0buf[1][rp][half ^ 1][l];
            // independent work under the read latency
            f32x4 xcn0 = MFMA(Aih, bxpack(xn0, g0), bias0);
            f32x4 xcn1 = MFMA(Aih, bxpack(xn1, g0), bias0);
            // tile 0 chain
            f16x8 B0 = half == 0 ? asm_frag(m0, s0) : asm_frag(s0, m0);
            f32x4 a0 = MFMA(Ahh, B0, xcA);
            // tile 1 chain (independent — fills tile 0's MFMA dep)
            f16x8 B1 = half == 0 ? asm_frag(m1, s1) : asm_frag(s1, m1);
            f32x4 a1 = MFMA(Ahh, B1, xcB);
            f32x4 t0, t1;
#pragma unroll
            for (int r = 0; r < 4; ++r) t0[r] = fast_tanh(a0[r]);
#pragma unroll
            for (int r = 0; r < 4; ++r) t1[r] = fast_tanh(a1[r]);
            m0 = pack_half(t0); h0buf[0][wpar][half][l] = m0;
            m1 = pack_half(t1); h0buf[1][wpar][half][l] = m1;
            xcA = xcn0; xcB = xcn1;
        };

        stepA(xa1, xb1, 0); bar_lds();   // i = 0
        stepA(xa2, xb2, 1); bar_lds();   // i = 1
        for (int tb = 0; tb < 128; ++tb) {
            const int i0 = 2 + tb * 4;
            float4 xn0[4], xn1[4];
#pragma unroll
            for (int u = 0; u < 4; ++u) {
                int idx = i0 + 5 + u;
                idx = idx < kT ? idx : (kT - 1);
                xn0[u] = ld4(xp0 + idx * kI);
                xn1[u] = ld4(xp1 + idx * kI);
            }
#pragma unroll
            for (int u = 0; u < 4; ++u) { stepA(xcur0[u], xcur1[u], i0 + u); bar_lds(); }
#pragma unroll
            for (int u = 0; u < 4; ++u) { xcur0[u] = xn0[u]; xcur1[u] = xn1[u]; }
        }
    } else {
        // ======== B-wave: layer 1 rows ro..ro+15 (+ head on half 0) ========
        const float* wp = W_ih1 + (c + ro) * kH;
        const f16x8 Aih1 = pack_frag(ld4(wp + k0), ld4(wp + 16 + k0));
        wp = W_hh1 + (c + ro) * kH;
        const f16x8 Ahh1 = pack_frag(ld4(wp + k0), ld4(wp + 16 + k0));
        const f16x8 All = (half == 0 && c < kO)
            ? pack_frag(ld4(W_ll + c * kH + k0), ld4(W_ll + c * kH + 16 + k0))
            : pack_frag(z4, z4);

        f32x4 bias1, biasll;
#pragma unroll
        for (int r = 0; r < 4; ++r) {
            bias1[r]  = b_ih1[ro + k0 + r] + b_hh1[ro + k0 + r];
            biasll[r] = g0 ? b_ll[r] : 0.f;
        }

        uint2 m0 = make_uint2(0u, 0u), m1 = make_uint2(0u, 0u);  // own h1 halves
        float* op0 = out + (size_t)b0 * (kT * kO);
        float* op1 = out + (size_t)b1 * (kT * kO);

        auto stepB = [&](int i, bool store) {
            const int rp = (i - 1) & 1, wpar = i & 1;
            // all 6 reads issue first
            uint2 h0lo0 = h0buf[0][rp][0][l], h0hi0 = h0buf[0][rp][1][l];
            uint2 h0lo1 = h0buf[1][rp][0][l], h0hi1 = h0buf[1][rp][1][l];
            uint2 s10 = h1buf[0][rp][half ^ 1][l];
            uint2 s11 = h1buf[1][rp][half ^ 1][l];
            // tile 0
            f16x8 Bh1_0 = half == 0 ? asm_frag(m0, s10) : asm_frag(s10, m0);
            f32x4 o0;
            if (half == 0) o0 = MFMA(All, Bh1_0, biasll);     // head, step i-2
            f32x4 cc0 = MFMA(Aih1, asm_frag(h0lo0, h0hi0), bias1);
            cc0 = MFMA(Ahh1, Bh1_0, cc0);
            // tile 1
            f16x8 Bh1_1 = half == 0 ? asm_frag(m1, s11) : asm_frag(s11, m1);
            f32x4 o1;
            if (half == 0) o1 = MFMA(All, Bh1_1, biasll);
            f32x4 cc1 = MFMA(Aih1, asm_frag(h0lo1, h0hi1), bias1);
            cc1 = MFMA(Ahh1, Bh1_1, cc1);

            f32x4 t0, t1;
#pragma unroll
            for (int r = 0; r < 4; ++r) t0[r] = fast_tanh(cc0[r]);
#pragma unroll
            for (int r = 0; r < 4; ++r) t1[r] = fast_tanh(cc1[r]);
            m0 = pack_half(t0); h1buf[0][wpar][half][l] = m0;
            m1 = pack_half(t1); h1buf[1][wpar][half][l] = m1;
            if (store && half == 0 && g0) {
                *(float4*)(op0 + (size_t)(i - 2) * kO) = make_float4(o0[0], o0[1], o0[2], o0[3]);
                *(float4*)(op1 + (size_t)(i - 2) * kO) = make_float4(o1[0], o1[1], o1[2], o1[3]);
            }
        };

        bar_lds();                    // i = 0: buffers already zero; just sync
        stepB(1, false); bar_lds();   // i = 1: h1[0] from h0[0], h1[-1]=0
        for (int tb = 0; tb < 128; ++tb) {
            const int i0 = 2 + tb * 4;
#pragma unroll
            for (int u = 0; u < 4; ++u) { stepB(i0 + u, true); bar_lds(); }
        }
    }
}

extern "C" void kernel_launch(void* const* d_in, const int* in_sizes, int n_in,
                              void* d_out, int out_size, void* d_ws, size_t ws_size,
                              hipStream_t stream) {
    const float* X     = (const float*)d_in[0];
    const float* W_ih0 = (const float*)d_in[1];
    const float* W_hh0 = (const float*)d_in[2];
    const float* b_ih0 = (const float*)d_in[3];
    const float* b_hh0 = (const float*)d_in[4];
    const float* W_ih1 = (const float*)d_in[5];
    const float* W_hh1 = (const float*)d_in[6];
    const float* b_ih1 = (const float*)d_in[7];
    const float* b_hh1 = (const float*)d_in[8];
    const float* W_ll  = (const float*)d_in[9];
    const float* b_ll  = (const float*)d_in[10];
    float* out = (float*)d_out;

    rnn2_quad2<<<dim3(kB / 32), dim3(256), 0, stream>>>(
        X, W_ih0, W_hh0, b_ih0, b_hh0, W_ih1, W_hh1, b_ih1, b_hh1, W_ll, b_ll, out);
}